// Round 1
// baseline (172.687 us; speedup 1.0000x reference)
//
#include <hip/hip_runtime.h>

#define DEV __device__ __forceinline__

constexpr int Bb    = 256;
constexpr int Ss    = 4096;
constexpr int HID_  = 16;
constexpr int VD_   = 6;
constexpr int WIN_  = 16;
constexpr int CHUNK = 512;
constexpr int WARM  = 128;
constexpr int SUB   = 32;
constexpr int NCHUNK = Ss / CHUNK;   // 8

// DPP row-rotate-by-1 within each 16-lane row. Direction (ror vs rol semantics)
// does not matter for correctness: the weight permutation below is built with
// the SAME op applied to a lane-index register, so they always agree.
DEV int   roti(int v)   { return __builtin_amdgcn_update_dpp(v, v, 0x121, 0xF, 0xF, true); }
DEV float rotf(float v) { return __int_as_float(roti(__float_as_int(v))); }
// lane <-> lane^16 exchange (BitMode swizzle: xor=0x10, and=0x1F)
DEV float swz16(float v){ return __int_as_float(__builtin_amdgcn_ds_swizzle(__float_as_int(v), 0x401F)); }

__global__ __launch_bounds__(64, 1) void bojanet_fused(
    const float* __restrict__ x,   const float* __restrict__ h0,
    const float* __restrict__ fIw, const float* __restrict__ fQw,
    const float* __restrict__ Wfi, const float* __restrict__ bfi,
    const float* __restrict__ Wfh, const float* __restrict__ Wgi,
    const float* __restrict__ bgi, const float* __restrict__ Wgh,
    const float* __restrict__ WoI, const float* __restrict__ boI,
    const float* __restrict__ WoQ, const float* __restrict__ boQ,
    float* __restrict__ out)
{
    // LDS: per-(t,b) slot layout, padded to dodge power-of-2 bank strides
    __shared__ float s_pre[64 * 36 + 8];  // [t*2+b][ fi(16) | gi(16) | pad(4) ]
    __shared__ float s_sc [64 * 12];      // [t*2+b][ cos(6) | sin(6) ]
    __shared__ float s_h  [64 * 20];      // [t*2+b][ h(16) | pad(4) ]

    const int lane = threadIdx.x;
    const int ci = blockIdx.x;       // chunk index
    const int b0 = blockIdx.y * 2;   // first of 2 batches

    // ---- S-phase roles: 4 rows of 16: (batch, f/g) x hidden j ----
    const int j  = lane & 15;
    const int r  = lane >> 4;
    const int fg = r & 1;            // 0: f-row (W_fh), 1: g-row (W_gh)
    const int bl = r >> 1;           // batch-local

    // ---- P/O-phase roles: one (t, batch) per lane ----
    const int pt = lane & 31;
    const int pb = lane >> 5;

    const int t_out0  = ci * CHUNK;
    const int t_start = (ci == 0) ? 0 : (t_out0 - WARM);
    const int t_end   = t_out0 + CHUNK;

    // rotation-consistent recurrence weights: wsel[i] = W[j][sigma^i(j)]
    const float* Wmat = fg ? Wgh : Wfh;
    float wsel[16];
    {
        int c = j;
        #pragma unroll
        for (int i = 0; i < 16; ++i) { wsel[i] = Wmat[j * 16 + c]; c = roti(c); }
    }
    // activation constants: f-rows sigmoid, g-rows tanh (both via 1/(1+2^(m*z)))
    const float mco = fg ? 2.885390081777927f : -1.4426950408889634f; // 2*log2e / -log2e
    const float Aco = fg ? -2.0f : 1.0f;
    const float Bco = fg ?  1.0f : 0.0f;

    float h = (ci == 0) ? h0[(b0 + bl) * HID_ + j] : 0.0f;

    for (int tb = t_start; tb < t_end; tb += SUB) {
        // ================= P: fi/gi + sin/cos for t in [tb, tb+SUB) ==========
        {
            const int t = tb + pt;
            const int b = b0 + pb;
            const float2* x2 = (const float2*)x + (size_t)b * Ss;
            float wIv[WIN_], wQv[WIN_];
            if (tb >= WIN_ - 1) {   // block-uniform: only chunk 0's first iter pads
                #pragma unroll
                for (int w = 0; w < WIN_; ++w) {
                    float2 v = x2[t - 15 + w];
                    wIv[w] = v.x; wQv[w] = v.y;
                }
            } else {
                #pragma unroll
                for (int w = 0; w < WIN_; ++w) {
                    int ts = t - 15 + w;
                    float2 v = (ts >= 0) ? x2[ts] : make_float2(0.f, 0.f);
                    wIv[w] = v.x; wQv[w] = v.y;
                }
            }
            // complex FIR: taps are wave-uniform -> scalar loads
            float aI[VD_], aQ[VD_];
            #pragma unroll
            for (int v = 0; v < VD_; ++v) { aI[v] = 0.f; aQ[v] = 0.f; }
            #pragma unroll
            for (int w = 0; w < WIN_; ++w) {
                #pragma unroll
                for (int v = 0; v < VD_; ++v) {
                    aI[v] = fmaf( wIv[w], fIw[v*16+w], aI[v]);
                    aI[v] = fmaf(-wQv[w], fQw[v*16+w], aI[v]);
                    aQ[v] = fmaf( wIv[w], fQw[v*16+w], aQ[v]);
                    aQ[v] = fmaf( wQv[w], fIw[v*16+w], aQ[v]);
                }
            }
            const int base = pt * 2 + pb;
            float L[12];
            #pragma unroll
            for (int v = 0; v < VD_; ++v) {
                float m2 = fmaf(aI[v], aI[v], aQ[v]*aQ[v]);
                float mg = __builtin_amdgcn_sqrtf(m2) + 1e-8f;
                float iv = __builtin_amdgcn_rcpf(mg);
                L[v] = mg; L[6+v] = mg*mg;
                s_sc[base*12 + v]     = aI[v] * iv;   // cos
                s_sc[base*12 + 6 + v] = aQ[v] * iv;   // sin
            }
            // fi/gi = b + W * L  (L-layout: [mag(6), mag2(6)])
            float fi[16], gi[16];
            #pragma unroll
            for (int k = 0; k < 16; ++k) { fi[k] = bfi[k]; gi[k] = bgi[k]; }
            #pragma unroll
            for (int l = 0; l < 12; ++l) {
                #pragma unroll
                for (int k = 0; k < 16; ++k) {
                    fi[k] = fmaf(L[l], Wfi[k*12+l], fi[k]);
                    gi[k] = fmaf(L[l], Wgi[k*12+l], gi[k]);
                }
            }
            #pragma unroll
            for (int k = 0; k < 16; ++k) {
                s_pre[base*36 + k]      = fi[k];
                s_pre[base*36 + 16 + k] = gi[k];
            }
        }
        __asm__ volatile("s_waitcnt lgkmcnt(0)" ::: "memory");

        // ================= S: 32 sequential recurrence steps ================
        {
            const int rbase = bl*36 + fg*16 + j;
            float pv0 = s_pre[rbase];          // step t prefetch pipeline (d=2)
            float pv1 = s_pre[72 + rbase];
            #pragma unroll 4
            for (int tt = 0; tt < SUB; ++tt) {
                int nx = (tt + 2 < SUB) ? (tt + 2) : (SUB - 1);
                float pvn = s_pre[nx*72 + rbase];
                float acc = pv0;               // fi (f-rows) / gi (g-rows)
                float hr = h;
                acc = fmaf(wsel[0], hr, acc);
                #pragma unroll
                for (int i = 1; i < 16; ++i) { hr = rotf(hr); acc = fmaf(wsel[i], hr, acc); }
                float e   = __builtin_amdgcn_exp2f(acc * mco);
                float u   = __builtin_amdgcn_rcpf(1.0f + e);
                float val = fmaf(Aco, u, Bco); // f-rows: sigmoid, g-rows: tanh
                float oth = swz16(val);        // exchange f<->g
                float F = fg ? oth : val;
                float G = fg ? val : oth;
                h = fmaf(F, h - G, G);         // h = f*h + (1-f)*g
                s_h[(tt*2 + bl)*20 + j] = h;
                pv0 = pv1; pv1 = pvn;
            }
        }
        __asm__ volatile("s_waitcnt lgkmcnt(0)" ::: "memory");

        // ================= O: rotated projection -> out =====================
        if (tb >= t_out0) {
            const int t = tb + pt;
            const int b = b0 + pb;
            const int base = pt*2 + pb;
            float hv[16], scv[12];
            #pragma unroll
            for (int k = 0; k < 16; ++k) hv[k]  = s_h[base*20 + k];
            #pragma unroll
            for (int k = 0; k < 12; ++k) scv[k] = s_sc[base*12 + k];
            float oI = boI[0], oQ = boQ[0];
            #pragma unroll
            for (int k = 0; k < 16; ++k) {
                int v = (k < 6) ? k : ((k < 12) ? k - 6 : k - 12); // theta tiling
                oI = fmaf(hv[k]*scv[v],   WoI[k], oI);
                oQ = fmaf(hv[k]*scv[6+v], WoQ[k], oQ);
            }
            float2 o; o.x = oI - oQ; o.y = oI + oQ;
            ((float2*)out)[(size_t)b * Ss + t] = o;
        }
    }
}

extern "C" void kernel_launch(void* const* d_in, const int* in_sizes, int n_in,
                              void* d_out, int out_size, void* d_ws, size_t ws_size,
                              hipStream_t stream) {
    const float* x   = (const float*)d_in[0];
    const float* h0  = (const float*)d_in[1];
    const float* fIw = (const float*)d_in[2];
    const float* fQw = (const float*)d_in[3];
    const float* Wfi = (const float*)d_in[4];
    const float* bfi = (const float*)d_in[5];
    const float* Wfh = (const float*)d_in[6];
    const float* Wgi = (const float*)d_in[7];
    const float* bgi = (const float*)d_in[8];
    const float* Wgh = (const float*)d_in[9];
    const float* WoI = (const float*)d_in[10];
    const float* boI = (const float*)d_in[11];
    const float* WoQ = (const float*)d_in[12];
    const float* boQ = (const float*)d_in[13];
    float* out = (float*)d_out;

    dim3 grid(NCHUNK, Bb / 2);
    bojanet_fused<<<grid, 64, 0, stream>>>(x, h0, fIw, fQw, Wfi, bfi, Wfh,
                                           Wgi, bgi, Wgh, WoI, boI, WoQ, boQ, out);
}

// Round 2
// 153.267 us; speedup vs baseline: 1.1267x; 1.1267x over previous
//
#include <hip/hip_runtime.h>

#define DEV __device__ __forceinline__

constexpr int Bb    = 256;
constexpr int Ss    = 4096;
constexpr int HIDN  = 16;
constexpr int VDN   = 6;
constexpr int WINN  = 16;
constexpr int CHUNK = 128;
constexpr int WARM  = 64;
constexpr int SUBN  = 16;
constexpr int NCHUNK = Ss / CHUNK;   // 32

// Independent row-rotate-by-K DPP movs (all sourced from the same reg).
// Direction-proof: the weight gather at init applies the SAME ctrl codes to a
// lane-index register, so weights and rotations always agree.
template<int C> DEV int   dpp_i(int v)  { return __builtin_amdgcn_update_dpp(0, v, C, 0xF, 0xF, false); }
template<int C> DEV float dpp_f(float v){ return __int_as_float(dpp_i<C>(__float_as_int(v))); }

#define DPP_ALL(X) X(1,0x121) X(2,0x122) X(3,0x123) X(4,0x124) X(5,0x125) X(6,0x126) X(7,0x127) \
  X(8,0x128) X(9,0x129) X(10,0x12A) X(11,0x12B) X(12,0x12C) X(13,0x12D) X(14,0x12E) X(15,0x12F)

__global__ __launch_bounds__(64, 2) void bojanet_v2(
    const float* __restrict__ x,   const float* __restrict__ h0,
    const float* __restrict__ fIw, const float* __restrict__ fQw,
    const float* __restrict__ Wfi, const float* __restrict__ bfi,
    const float* __restrict__ Wfh, const float* __restrict__ Wgi,
    const float* __restrict__ bgi, const float* __restrict__ Wgh,
    const float* __restrict__ WoI, const float* __restrict__ boI,
    const float* __restrict__ WoQ, const float* __restrict__ boQ,
    float* __restrict__ out)
{
    // strides padded so wave64 accesses stay <=~3-way on 32 banks
    __shared__ __align__(16) float s_fi[SUBN * 80];   // [t][b*20 + j]
    __shared__ __align__(16) float s_gi[SUBN * 80];
    __shared__ __align__(16) float s_h [SUBN * 68];   // [t][b*16 + j]
    __shared__ float s_sc[4 * 12 * 17];               // [b][k][t], t-stride 17

    const int lane = threadIdx.x;
    const int j  = lane & 15;   // S: hidden unit ; P/O: time slot
    const int bl = lane >> 4;   // batch-local 0..3 (all phases)

    const int ci = blockIdx.x;
    const int b0 = blockIdx.y * 4;
    const int t_out0  = ci * CHUNK;
    const int t_start = ci ? (t_out0 - WARM) : 0;
    const int t_end   = t_out0 + CHUNK;

    // rotation-consistent weight gather: c[k] = sigma_k(j) via identical DPP ctrls
    int c[16]; c[0] = j;
#define CSET(K,CTL) c[K] = dpp_i<CTL>(j);
    DPP_ALL(CSET)
#undef CSET
    float wf[16], wg[16];
#pragma unroll
    for (int k = 0; k < 16; ++k) { wf[k] = Wfh[j*16 + c[k]]; wg[k] = Wgh[j*16 + c[k]]; }

    float h = (ci == 0) ? h0[(b0 + bl) * HIDN + j] : 0.0f;

    const float2* x2  = (const float2*)x   + (size_t)(b0 + bl) * Ss;
    float2*       out2 = (float2*)out      + (size_t)(b0 + bl) * Ss;

    for (int tb = t_start; tb < t_end; tb += SUBN) {
        const bool emit = (tb >= t_out0);

        // ================= P: fi/gi (+cos/sin) for 16 t x 4 b, one item/lane =
        {
            const int tg = tb + j;
            float wI[WINN], wQ[WINN];
            if (tb >= WINN - 1) {
#pragma unroll
                for (int w = 0; w < WINN; ++w) { float2 v = x2[tg - 15 + w]; wI[w] = v.x; wQ[w] = v.y; }
            } else {
#pragma unroll
                for (int w = 0; w < WINN; ++w) {
                    int ts = tg - 15 + w;
                    float2 v = (ts >= 0) ? x2[ts] : make_float2(0.f, 0.f);
                    wI[w] = v.x; wQ[w] = v.y;
                }
            }
            float aI[VDN], aQ[VDN];
#pragma unroll
            for (int v = 0; v < VDN; ++v) { aI[v] = 0.f; aQ[v] = 0.f; }
#pragma unroll
            for (int w = 0; w < WINN; ++w) {
#pragma unroll
                for (int v = 0; v < VDN; ++v) {
                    aI[v] = fmaf( wI[w], fIw[v*16+w], aI[v]);
                    aI[v] = fmaf(-wQ[w], fQw[v*16+w], aI[v]);
                    aQ[v] = fmaf( wI[w], fQw[v*16+w], aQ[v]);
                    aQ[v] = fmaf( wQ[w], fIw[v*16+w], aQ[v]);
                }
            }
            float L[12];
#pragma unroll
            for (int v = 0; v < VDN; ++v) {
                float m2 = fmaf(aI[v], aI[v], aQ[v]*aQ[v]);
                float mg = __builtin_amdgcn_sqrtf(m2) + 1e-8f;
                L[v] = mg; L[6+v] = mg*mg;
                if (emit) {
                    float iv = __builtin_amdgcn_rcpf(mg);
                    s_sc[(bl*12 + v  )*17 + j] = aI[v] * iv;   // cos
                    s_sc[(bl*12 + 6+v)*17 + j] = aQ[v] * iv;   // sin
                }
            }
            float fi[16], gi[16];
#pragma unroll
            for (int k = 0; k < 16; ++k) { fi[k] = bfi[k]; gi[k] = bgi[k]; }
#pragma unroll
            for (int l = 0; l < 12; ++l) {
#pragma unroll
                for (int k = 0; k < 16; ++k) {
                    fi[k] = fmaf(L[l], Wfi[k*12+l], fi[k]);
                    gi[k] = fmaf(L[l], Wgi[k*12+l], gi[k]);
                }
            }
            float* pf = &s_fi[j*80 + bl*20];
            float* pg = &s_gi[j*80 + bl*20];
#pragma unroll
            for (int q = 0; q < 4; ++q) {
                *(float4*)(pf + 4*q) = make_float4(fi[4*q], fi[4*q+1], fi[4*q+2], fi[4*q+3]);
                *(float4*)(pg + 4*q) = make_float4(gi[4*q], gi[4*q+1], gi[4*q+2], gi[4*q+3]);
            }
        }
        __asm__ volatile("s_waitcnt lgkmcnt(0)" ::: "memory");

        // ================= S: 16 sequential steps, f&g fused per lane =========
        {
            const int rb = bl*20 + j;
            float pf0 = s_fi[rb], pf1 = s_fi[80 + rb];
            float pg0 = s_gi[rb], pg1 = s_gi[80 + rb];
#pragma unroll
            for (int tt = 0; tt < SUBN; ++tt) {
                const int nx = (tt + 2 < SUBN) ? tt + 2 : SUBN - 1;
                float pfn = s_fi[nx*80 + rb];
                float pgn = s_gi[nx*80 + rb];
                float hr[16]; hr[0] = h;
#define HSET(K,CTL) hr[K] = dpp_f<CTL>(h);
                DPP_ALL(HSET)
#undef HSET
                float af0 = pf0, af1 = 0.f, ag0 = pg0, ag1 = 0.f;
#pragma unroll
                for (int k = 0; k < 8; ++k) {
                    af0 = fmaf(wf[k],   hr[k],   af0);
                    ag0 = fmaf(wg[k],   hr[k],   ag0);
                    af1 = fmaf(wf[k+8], hr[k+8], af1);
                    ag1 = fmaf(wg[k+8], hr[k+8], ag1);
                }
                float zf = af0 + af1, zg = ag0 + ag1;
                float f = __builtin_amdgcn_rcpf(1.0f + __builtin_amdgcn_exp2f(zf * -1.4426950408889634f));
                float g = fmaf(-2.0f, __builtin_amdgcn_rcpf(1.0f + __builtin_amdgcn_exp2f(zg * 2.8853900817779268f)), 1.0f);
                h = fmaf(f, h - g, g);
                s_h[tt*68 + bl*16 + j] = h;
                pf0 = pf1; pf1 = pfn; pg0 = pg1; pg1 = pgn;
            }
        }
        __asm__ volatile("s_waitcnt lgkmcnt(0)" ::: "memory");

        // ================= O: rotated projection, one (t,b)/lane ==============
        if (emit) {
            const int tg = tb + j;
            float hv[16];
#pragma unroll
            for (int q = 0; q < 4; ++q) {
                float4 t4 = *(const float4*)&s_h[j*68 + bl*16 + 4*q];
                hv[4*q] = t4.x; hv[4*q+1] = t4.y; hv[4*q+2] = t4.z; hv[4*q+3] = t4.w;
            }
            float cs[12];
#pragma unroll
            for (int k = 0; k < 12; ++k) cs[k] = s_sc[(bl*12 + k)*17 + j];
            float oI = boI[0], oQ = boQ[0];
#pragma unroll
            for (int k = 0; k < 16; ++k) {
                int v = (k < 6) ? k : ((k < 12) ? k - 6 : k - 12); // theta tiling
                oI = fmaf(hv[k]*cs[v],   WoI[k], oI);
                oQ = fmaf(hv[k]*cs[6+v], WoQ[k], oQ);
            }
            out2[tg] = make_float2(oI - oQ, oI + oQ);
        }
        __asm__ volatile("s_waitcnt lgkmcnt(0)" ::: "memory");
    }
}

extern "C" void kernel_launch(void* const* d_in, const int* in_sizes, int n_in,
                              void* d_out, int out_size, void* d_ws, size_t ws_size,
                              hipStream_t stream) {
    const float* x   = (const float*)d_in[0];
    const float* h0  = (const float*)d_in[1];
    const float* fIw = (const float*)d_in[2];
    const float* fQw = (const float*)d_in[3];
    const float* Wfi = (const float*)d_in[4];
    const float* bfi = (const float*)d_in[5];
    const float* Wfh = (const float*)d_in[6];
    const float* Wgi = (const float*)d_in[7];
    const float* bgi = (const float*)d_in[8];
    const float* Wgh = (const float*)d_in[9];
    const float* WoI = (const float*)d_in[10];
    const float* boI = (const float*)d_in[11];
    const float* WoQ = (const float*)d_in[12];
    const float* boQ = (const float*)d_in[13];
    float* out = (float*)d_out;

    dim3 grid(NCHUNK, Bb / 4);
    bojanet_v2<<<grid, 64, 0, stream>>>(x, h0, fIw, fQw, Wfi, bfi, Wfh,
                                        Wgi, bgi, Wgh, WoI, boI, WoQ, boQ, out);
}

// Round 4
// 103.196 us; speedup vs baseline: 1.6734x; 1.4852x over previous
//
#include <hip/hip_runtime.h>
#include <stdint.h>

#define DEV __device__ __forceinline__

constexpr int Bb   = 256;
constexpr int Ss   = 4096;
constexpr int HIDN = 16;
constexpr int VDN  = 6;
constexpr int WINN = 16;

// K2 chunking
constexpr int CHUNK = 64;
constexpr int WARM  = 32;
constexpr int SUBN  = 16;
constexpr int NCHUNK = Ss / CHUNK;                 // 64
constexpr long long NITEM = (long long)Bb * Ss;    // 1,048,576
constexpr size_t WS0_BYTES = (size_t)NITEM * 16 * 4;  // fi/gi packed f16 pairs
constexpr size_t WS1_BYTES = (size_t)NITEM * 6 * 4;   // cos/sin packed f16 pairs

// Independent row-rotate-by-K DPP movs. Direction-proof: the weight gather
// applies the SAME ctrl codes to a lane-index register.
template<int C> DEV int   dpp_i(int v)  { return __builtin_amdgcn_update_dpp(0, v, C, 0xF, 0xF, false); }
template<int C> DEV float dpp_f(float v){ return __int_as_float(dpp_i<C>(__float_as_int(v))); }

#define DPP_ALL(X) X(1,0x121) X(2,0x122) X(3,0x123) X(4,0x124) X(5,0x125) X(6,0x126) X(7,0x127) \
  X(8,0x128) X(9,0x129) X(10,0x12A) X(11,0x12B) X(12,0x12C) X(13,0x12D) X(14,0x12E) X(15,0x12F)

typedef __fp16 h2v __attribute__((ext_vector_type(2)));
DEV uint32_t pk16(float a, float b) {
    h2v t = __builtin_amdgcn_cvt_pkrtz(a, b);
    uint32_t u; __builtin_memcpy(&u, &t, 4); return u;
}
DEV void up16(uint32_t u, float& a, float& b) {
    h2v t; __builtin_memcpy(&t, &u, 4);
    a = (float)t[0]; b = (float)t[1];
}

// ======================= K1: parallel precompute ============================
__global__ __launch_bounds__(256, 4) void boja_pre(
    const float* __restrict__ x,
    const float* __restrict__ fIw, const float* __restrict__ fQw,
    const float* __restrict__ Wfi, const float* __restrict__ bfi,
    const float* __restrict__ Wgi, const float* __restrict__ bgi,
    uint32_t* __restrict__ ws0, uint32_t* __restrict__ ws1)
{
    const int id = blockIdx.x * 256 + threadIdx.x;   // id = b*Ss + t
    const int t  = id & (Ss - 1);
    const float2* x2 = (const float2*)x;

    float wI[WINN], wQ[WINN];
    if (t >= WINN - 1) {
#pragma unroll
        for (int w = 0; w < WINN; ++w) { float2 v = x2[id - 15 + w]; wI[w] = v.x; wQ[w] = v.y; }
    } else {
#pragma unroll
        for (int w = 0; w < WINN; ++w) {
            int ts = t - 15 + w;
            float2 v = (ts >= 0) ? x2[id - 15 + w] : make_float2(0.f, 0.f);
            wI[w] = v.x; wQ[w] = v.y;
        }
    }
    float aI[VDN], aQ[VDN];
#pragma unroll
    for (int v = 0; v < VDN; ++v) { aI[v] = 0.f; aQ[v] = 0.f; }
#pragma unroll
    for (int w = 0; w < WINN; ++w) {
#pragma unroll
        for (int v = 0; v < VDN; ++v) {
            aI[v] = fmaf( wI[w], fIw[v*16+w], aI[v]);
            aI[v] = fmaf(-wQ[w], fQw[v*16+w], aI[v]);
            aQ[v] = fmaf( wI[w], fQw[v*16+w], aQ[v]);
            aQ[v] = fmaf( wQ[w], fIw[v*16+w], aQ[v]);
        }
    }
    float L[12];
    uint32_t sc[6];
#pragma unroll
    for (int v = 0; v < VDN; ++v) {
        float m2 = fmaf(aI[v], aI[v], aQ[v]*aQ[v]);
        float mg = __builtin_amdgcn_sqrtf(m2) + 1e-8f;
        float iv = __builtin_amdgcn_rcpf(mg);
        L[v] = mg; L[6+v] = mg*mg;
        sc[v] = pk16(aI[v]*iv, aQ[v]*iv);   // (cos, sin)
    }
    float fi[16], gi[16];
#pragma unroll
    for (int k = 0; k < 16; ++k) { fi[k] = bfi[k]; gi[k] = bgi[k]; }
#pragma unroll
    for (int l = 0; l < 12; ++l) {
#pragma unroll
        for (int k = 0; k < 16; ++k) {
            fi[k] = fmaf(L[l], Wfi[k*12+l], fi[k]);
            gi[k] = fmaf(L[l], Wgi[k*12+l], gi[k]);
        }
    }
    uint32_t fg[16];
#pragma unroll
    for (int k = 0; k < 16; ++k) fg[k] = pk16(fi[k], gi[k]);
    uint4* p0 = (uint4*)(ws0 + (size_t)id * 16);
#pragma unroll
    for (int q = 0; q < 4; ++q)
        p0[q] = make_uint4(fg[4*q], fg[4*q+1], fg[4*q+2], fg[4*q+3]);
    uint2* p1 = (uint2*)(ws1 + (size_t)id * 6);
    p1[0] = make_uint2(sc[0], sc[1]);
    p1[1] = make_uint2(sc[2], sc[3]);
    p1[2] = make_uint2(sc[4], sc[5]);
}

// ======================= K2: recurrence + output ============================
__global__ __launch_bounds__(64, 4) void boja_rec(
    const uint32_t* __restrict__ ws0, const uint32_t* __restrict__ ws1,
    const float* __restrict__ h0,
    const float* __restrict__ Wfh, const float* __restrict__ Wgh,
    const float* __restrict__ WoI, const float* __restrict__ boI,
    const float* __restrict__ WoQ, const float* __restrict__ boQ,
    float* __restrict__ out)
{
    __shared__ float s_h[SUBN * 68];   // [tt][bl*16 + j], stride 68 pads banks

    const int lane = threadIdx.x;
    const int j  = lane & 15;
    const int bl = lane >> 4;

    const int ci = blockIdx.x;
    const int b0 = blockIdx.y * 4;
    const int t_out0  = ci * CHUNK;
    const int t_start = ci ? (t_out0 - WARM) : 0;
    const int t_end   = t_out0 + CHUNK;

    // rotation-consistent weight gather
    int c[16]; c[0] = j;
#define CSET(K,CTL) c[K] = dpp_i<CTL>(j);
    DPP_ALL(CSET)
#undef CSET
    float wf[16], wg[16];
#pragma unroll
    for (int k = 0; k < 16; ++k) { wf[k] = Wfh[j*16 + c[k]]; wg[k] = Wgh[j*16 + c[k]]; }

    float h = (ci == 0) ? h0[(b0 + bl) * HIDN + j] : 0.0f;

    const uint32_t* fgp = ws0 + (size_t)(b0 + bl) * Ss * 16 + j;

    for (int tb = t_start; tb < t_end; tb += SUBN) {
        // 16-deep prefetch of packed (fi,gi): one dword per step, single base
        uint32_t pf[SUBN];
#pragma unroll
        for (int tt = 0; tt < SUBN; ++tt) pf[tt] = fgp[(size_t)(tb + tt) * 16];

#pragma unroll
        for (int tt = 0; tt < SUBN; ++tt) {
            float fiv, giv; up16(pf[tt], fiv, giv);
            float hr[16]; hr[0] = h;
#define HSET(K,CTL) hr[K] = dpp_f<CTL>(h);
            DPP_ALL(HSET)
#undef HSET
            float af0 = fiv, af1 = 0.f, ag0 = giv, ag1 = 0.f;
#pragma unroll
            for (int k = 0; k < 8; ++k) {
                af0 = fmaf(wf[k],   hr[k],   af0);
                ag0 = fmaf(wg[k],   hr[k],   ag0);
                af1 = fmaf(wf[k+8], hr[k+8], af1);
                ag1 = fmaf(wg[k+8], hr[k+8], ag1);
            }
            float zf = af0 + af1, zg = ag0 + ag1;
            float f = __builtin_amdgcn_rcpf(1.0f + __builtin_amdgcn_exp2f(zf * -1.4426950408889634f));
            float g = fmaf(-2.0f, __builtin_amdgcn_rcpf(1.0f + __builtin_amdgcn_exp2f(zg * 2.8853900817779268f)), 1.0f);
            h = fmaf(f, h - g, g);
            s_h[tt*68 + bl*16 + j] = h;
        }
        __asm__ volatile("s_waitcnt lgkmcnt(0)" ::: "memory");

        // O: rotated projection, one (t,b) per lane
        if (tb >= t_out0) {
            const int tloc = lane & 15, bq = lane >> 4;
            const int tg = tb + tloc;
            const size_t item = (size_t)(b0 + bq) * Ss + tg;
            float hv[16];
#pragma unroll
            for (int q = 0; q < 4; ++q) {
                float4 v4 = *(const float4*)&s_h[tloc*68 + bq*16 + 4*q];
                hv[4*q] = v4.x; hv[4*q+1] = v4.y; hv[4*q+2] = v4.z; hv[4*q+3] = v4.w;
            }
            const uint2* p1 = (const uint2*)(ws1 + item * 6);
            uint2 r0 = p1[0], r1 = p1[1], r2 = p1[2];
            float cs[12];
            up16(r0.x, cs[0], cs[6]); up16(r0.y, cs[1], cs[7]);
            up16(r1.x, cs[2], cs[8]); up16(r1.y, cs[3], cs[9]);
            up16(r2.x, cs[4], cs[10]); up16(r2.y, cs[5], cs[11]);
            float oI = boI[0], oQ = boQ[0];
#pragma unroll
            for (int k = 0; k < 16; ++k) {
                int v = (k < 6) ? k : ((k < 12) ? k - 6 : k - 12);
                oI = fmaf(hv[k]*cs[v],   WoI[k], oI);
                oQ = fmaf(hv[k]*cs[6+v], WoQ[k], oQ);
            }
            ((float2*)out)[item] = make_float2(oI - oQ, oI + oQ);
        }
        __asm__ volatile("s_waitcnt lgkmcnt(0)" ::: "memory");
    }
}

// ======================= Fallback (known-good v2) ===========================
__global__ __launch_bounds__(64, 2) void bojanet_v2(
    const float* __restrict__ x,   const float* __restrict__ h0,
    const float* __restrict__ fIw, const float* __restrict__ fQw,
    const float* __restrict__ Wfi, const float* __restrict__ bfi,
    const float* __restrict__ Wfh, const float* __restrict__ Wgi,
    const float* __restrict__ bgi, const float* __restrict__ Wgh,
    const float* __restrict__ WoI, const float* __restrict__ boI,
    const float* __restrict__ WoQ, const float* __restrict__ boQ,
    float* __restrict__ out)
{
    constexpr int FCH = 128, FWR = 64, FSB = 16;
    __shared__ __align__(16) float s_fi[FSB * 80];
    __shared__ __align__(16) float s_gi[FSB * 80];
    __shared__ __align__(16) float s_h [FSB * 68];
    __shared__ float s_sc[4 * 12 * 17];

    const int lane = threadIdx.x;
    const int j  = lane & 15;
    const int bl = lane >> 4;
    const int ci = blockIdx.x;
    const int b0 = blockIdx.y * 4;
    const int t_out0  = ci * FCH;
    const int t_start = ci ? (t_out0 - FWR) : 0;
    const int t_end   = t_out0 + FCH;

    int c[16]; c[0] = j;
#define CSET(K,CTL) c[K] = dpp_i<CTL>(j);
    DPP_ALL(CSET)
#undef CSET
    float wf[16], wg[16];
#pragma unroll
    for (int k = 0; k < 16; ++k) { wf[k] = Wfh[j*16 + c[k]]; wg[k] = Wgh[j*16 + c[k]]; }

    float h = (ci == 0) ? h0[(b0 + bl) * HIDN + j] : 0.0f;
    const float2* x2   = (const float2*)x + (size_t)(b0 + bl) * Ss;
    float2*       out2 = (float2*)out     + (size_t)(b0 + bl) * Ss;

    for (int tb = t_start; tb < t_end; tb += FSB) {
        const bool emit = (tb >= t_out0);
        {
            const int tg = tb + j;
            float wI[WINN], wQ[WINN];
            if (tb >= WINN - 1) {
#pragma unroll
                for (int w = 0; w < WINN; ++w) { float2 v = x2[tg - 15 + w]; wI[w] = v.x; wQ[w] = v.y; }
            } else {
#pragma unroll
                for (int w = 0; w < WINN; ++w) {
                    int ts = tg - 15 + w;
                    float2 v = (ts >= 0) ? x2[ts] : make_float2(0.f, 0.f);
                    wI[w] = v.x; wQ[w] = v.y;
                }
            }
            float aI[VDN], aQ[VDN];
#pragma unroll
            for (int v = 0; v < VDN; ++v) { aI[v] = 0.f; aQ[v] = 0.f; }
#pragma unroll
            for (int w = 0; w < WINN; ++w) {
#pragma unroll
                for (int v = 0; v < VDN; ++v) {
                    aI[v] = fmaf( wI[w], fIw[v*16+w], aI[v]);
                    aI[v] = fmaf(-wQ[w], fQw[v*16+w], aI[v]);
                    aQ[v] = fmaf( wI[w], fQw[v*16+w], aQ[v]);
                    aQ[v] = fmaf( wQ[w], fIw[v*16+w], aQ[v]);
                }
            }
            float L[12];
#pragma unroll
            for (int v = 0; v < VDN; ++v) {
                float m2 = fmaf(aI[v], aI[v], aQ[v]*aQ[v]);
                float mg = __builtin_amdgcn_sqrtf(m2) + 1e-8f;
                L[v] = mg; L[6+v] = mg*mg;
                if (emit) {
                    float iv = __builtin_amdgcn_rcpf(mg);
                    s_sc[(bl*12 + v  )*17 + j] = aI[v] * iv;
                    s_sc[(bl*12 + 6+v)*17 + j] = aQ[v] * iv;
                }
            }
            float fi[16], gi[16];
#pragma unroll
            for (int k = 0; k < 16; ++k) { fi[k] = bfi[k]; gi[k] = bgi[k]; }
#pragma unroll
            for (int l = 0; l < 12; ++l) {
#pragma unroll
                for (int k = 0; k < 16; ++k) {
                    fi[k] = fmaf(L[l], Wfi[k*12+l], fi[k]);
                    gi[k] = fmaf(L[l], Wgi[k*12+l], gi[k]);
                }
            }
            float* pf = &s_fi[j*80 + bl*20];
            float* pg = &s_gi[j*80 + bl*20];
#pragma unroll
            for (int q = 0; q < 4; ++q) {
                *(float4*)(pf + 4*q) = make_float4(fi[4*q], fi[4*q+1], fi[4*q+2], fi[4*q+3]);
                *(float4*)(pg + 4*q) = make_float4(gi[4*q], gi[4*q+1], gi[4*q+2], gi[4*q+3]);
            }
        }
        __asm__ volatile("s_waitcnt lgkmcnt(0)" ::: "memory");
        {
            const int rb = bl*20 + j;
            float pf0 = s_fi[rb], pf1 = s_fi[80 + rb];
            float pg0 = s_gi[rb], pg1 = s_gi[80 + rb];
#pragma unroll
            for (int tt = 0; tt < FSB; ++tt) {
                const int nx = (tt + 2 < FSB) ? tt + 2 : FSB - 1;
                float pfn = s_fi[nx*80 + rb];
                float pgn = s_gi[nx*80 + rb];
                float hr[16]; hr[0] = h;
#define HSET(K,CTL) hr[K] = dpp_f<CTL>(h);
                DPP_ALL(HSET)
#undef HSET
                float af0 = pf0, af1 = 0.f, ag0 = pg0, ag1 = 0.f;
#pragma unroll
                for (int k = 0; k < 8; ++k) {
                    af0 = fmaf(wf[k],   hr[k],   af0);
                    ag0 = fmaf(wg[k],   hr[k],   ag0);
                    af1 = fmaf(wf[k+8], hr[k+8], af1);
                    ag1 = fmaf(wg[k+8], hr[k+8], ag1);
                }
                float zf = af0 + af1, zg = ag0 + ag1;
                float f = __builtin_amdgcn_rcpf(1.0f + __builtin_amdgcn_exp2f(zf * -1.4426950408889634f));
                float g = fmaf(-2.0f, __builtin_amdgcn_rcpf(1.0f + __builtin_amdgcn_exp2f(zg * 2.8853900817779268f)), 1.0f);
                h = fmaf(f, h - g, g);
                s_h[tt*68 + bl*16 + j] = h;
                pf0 = pf1; pf1 = pfn; pg0 = pg1; pg1 = pgn;
            }
        }
        __asm__ volatile("s_waitcnt lgkmcnt(0)" ::: "memory");
        if (emit) {
            const int tg = tb + j;
            float hv[16];
#pragma unroll
            for (int q = 0; q < 4; ++q) {
                float4 t4 = *(const float4*)&s_h[j*68 + bl*16 + 4*q];
                hv[4*q] = t4.x; hv[4*q+1] = t4.y; hv[4*q+2] = t4.z; hv[4*q+3] = t4.w;
            }
            float cs[12];
#pragma unroll
            for (int k = 0; k < 12; ++k) cs[k] = s_sc[(bl*12 + k)*17 + j];
            float oI = boI[0], oQ = boQ[0];
#pragma unroll
            for (int k = 0; k < 16; ++k) {
                int v = (k < 6) ? k : ((k < 12) ? k - 6 : k - 12);
                oI = fmaf(hv[k]*cs[v],   WoI[k], oI);
                oQ = fmaf(hv[k]*cs[6+v], WoQ[k], oQ);
            }
            out2[tg] = make_float2(oI - oQ, oI + oQ);
        }
        __asm__ volatile("s_waitcnt lgkmcnt(0)" ::: "memory");
    }
}

extern "C" void kernel_launch(void* const* d_in, const int* in_sizes, int n_in,
                              void* d_out, int out_size, void* d_ws, size_t ws_size,
                              hipStream_t stream) {
    const float* x   = (const float*)d_in[0];
    const float* h0  = (const float*)d_in[1];
    const float* fIw = (const float*)d_in[2];
    const float* fQw = (const float*)d_in[3];
    const float* Wfi = (const float*)d_in[4];
    const float* bfi = (const float*)d_in[5];
    const float* Wfh = (const float*)d_in[6];
    const float* Wgi = (const float*)d_in[7];
    const float* bgi = (const float*)d_in[8];
    const float* Wgh = (const float*)d_in[9];
    const float* WoI = (const float*)d_in[10];
    const float* boI = (const float*)d_in[11];
    const float* WoQ = (const float*)d_in[12];
    const float* boQ = (const float*)d_in[13];
    float* out = (float*)d_out;

    if (ws_size >= WS0_BYTES + WS1_BYTES) {
        uint32_t* ws0 = (uint32_t*)d_ws;
        uint32_t* ws1 = (uint32_t*)((char*)d_ws + WS0_BYTES);
        boja_pre<<<dim3((unsigned)(NITEM / 256)), 256, 0, stream>>>(
            x, fIw, fQw, Wfi, bfi, Wgi, bgi, ws0, ws1);
        boja_rec<<<dim3(NCHUNK, Bb / 4), 64, 0, stream>>>(
            ws0, ws1, h0, Wfh, Wgh, WoI, boI, WoQ, boQ, out);
    } else {
        bojanet_v2<<<dim3(32, Bb / 4), 64, 0, stream>>>(
            x, h0, fIw, fQw, Wfi, bfi, Wfh, Wgi, bgi, Wgh, WoI, boI, WoQ, boQ, out);
    }
}